// Round 13
// baseline (92.259 us; speedup 1.0000x reference)
//
#include <hip/hip_runtime.h>
#include <stdint.h>
#include <stddef.h>

typedef int   v4i  __attribute__((ext_vector_type(4)));
typedef int   v16i __attribute__((ext_vector_type(16)));
typedef float v4f  __attribute__((ext_vector_type(4)));

#define M_DIM 32768
#define N_DIM 1024
#define K_DIM 1024
#define BM 64            // rows per block; block owns [64][1024] of out
#define KSTEPS 16        // K=1024 / 64

// ---------------- pass 0: repack W int32 [N][K] -> fragment-linear int8 -----
// 32x32 B-frag: lane ln holds n = base + (ln&31), k-half (ln>>5)*16.
// Frag id f = (((np*8 + wv)*16 + ks)*2 + ksub)*2 + j; wave (np,wv) at kstep ks
// reads frags [fbase, fbase+4) = 4 KB contiguous.
__global__ __launch_bounds__(256)
void repack_w_kernel(const int* __restrict__ w32, int* __restrict__ wf)
{
    const int i  = blockIdx.x * 256 + threadIdx.x;   // dword index, < 262144
    const int f  = i >> 8;            // fragment id 0..1023
    const int r  = i & 255;
    const int ln = r >> 2;            // lane 0..63
    const int dw = r & 3;             // dword within 16B
    const int j    = f & 1;
    const int ksub = (f >> 1) & 1;
    const int ks   = (f >> 2) & 15;
    const int wv   = (f >> 6) & 7;
    const int np   = f >> 9;
    const int n  = np * 512 + wv * 64 + j * 32 + (ln & 31);
    const int k  = ks * 64 + ksub * 32 + (ln >> 5) * 16 + dw * 4;
    const v4i v  = *(const v4i*)&w32[(size_t)n * K_DIM + k];
    wf[i] = (v[0] & 255) | ((v[1] & 255) << 8) |
            ((v[2] & 255) << 16) | ((v[3] & 255) << 24);
}

// ---------------- fused: quantize x -> LDS, then int8 GEMM + dequant --------
// 512 threads = 8 waves; wave owns [64m][64n] per n-pass = 2x2 of 32x32x32
// i8 MFMA (acc 2x2 v16i = 64 regs), 2 passes cover N=1024.
// B-frags PREFETCHED one kstep ahead (bC/bN static alternation, unroll 2):
// ~320 cy of MFMA covers the L2 latency of the next 4 KB B-group.
// Operand-swapped mfma(W, A): n on reg-dim -> v4f contiguous stores.
__global__ __launch_bounds__(512, 4)
void fused_kernel(const float* __restrict__ x,
                  const signed char* __restrict__ Wf,
                  const float* __restrict__ wscale,
                  const float* __restrict__ iscale_p,
                  const float* __restrict__ bias,
                  float* __restrict__ out)
{
    __shared__ signed char lA[BM * K_DIM];   // 64 KiB, swizzled col^((row&7)<<4)

    const int mrow0 = blockIdx.x * BM;
    const int t  = threadIdx.x;
    const int wv = t >> 6;
    const int ln = t & 63;
    const int lm = ln & 31;              // m-row within 32-strip (A lane dim)
    const int kq = (ln >> 5) * 16;       // k-half byte offset

    // ---- phase 1: load fp32 slab, quantize, swizzled LDS write (R8-proven)
    {
        const float inv = 1.0f / *iscale_p;
        const int colf = (t & 255) * 4;          // int8/float column
        const int rsub = t >> 8;                 // 0..1
        for (int j = 0; j < 32; ++j) {
            const int row = j * 2 + rsub;
            const v4f v = *(const v4f*)&x[(size_t)(mrow0 + row) * K_DIM + colf];
            int r = 0;
            #pragma unroll
            for (int e = 0; e < 4; ++e) {
                float q = rintf(v[e] * inv);     // round-half-even like jnp
                q = fminf(127.f, fmaxf(-128.f, q));
                r |= ((int)q & 255) << (8 * e);
            }
            *(int*)&lA[row * K_DIM + (colf ^ ((row & 7) << 4))] = r;
        }
    }
    __syncthreads();   // the only barrier: LDS A-tile complete

    const float is = *iscale_p;

    // fragment base address helper: u = np*16 + ks in [0,32)
    #define FBASE(u) ((((size_t)(u >> 4) * 8 + wv) * 16 + (u & 15)) * 4)

    v4i bC[4], bN[4];
    #pragma unroll
    for (int q = 0; q < 4; ++q)
        bC[q] = *(const v4i*)&Wf[(FBASE(0) + q) * 1024 + ln * 16];

    v16i acc[2][2] = {};
    #pragma unroll 2
    for (int u = 0; u < 32; ++u) {
        const int np = u >> 4;
        const int ks = u & 15;
        const int un = (u + 1 < 32) ? u + 1 : 31;   // last prefetch harmless
        // prefetch next kstep's B-group (other buffer; parity static)
        if ((u & 1) == 0) {
            #pragma unroll
            for (int q = 0; q < 4; ++q)
                bN[q] = *(const v4i*)&Wf[(FBASE(un) + q) * 1024 + ln * 16];
        } else {
            #pragma unroll
            for (int q = 0; q < 4; ++q)
                bC[q] = *(const v4i*)&Wf[(FBASE(un) + q) * 1024 + ln * 16];
        }
        // A-frags from LDS: aF[i][ksub], row = i*32 + lm
        v4i aF[2][2];
        #pragma unroll
        for (int i = 0; i < 2; ++i) {
            const int row = i * 32 + lm;
            #pragma unroll
            for (int s = 0; s < 2; ++s)
                aF[i][s] = *(const v4i*)&lA[row * K_DIM +
                             ((ks * 64 + s * 32 + kq) ^ ((row & 7) << 4))];
        }
        // 8 MFMA with the CURRENT buffer (parity static): frag q = ksub*2 + j
        if ((u & 1) == 0) {
            #pragma unroll
            for (int i = 0; i < 2; ++i)
                #pragma unroll
                for (int j = 0; j < 2; ++j)
                    #pragma unroll
                    for (int s = 0; s < 2; ++s)
                        acc[i][j] = __builtin_amdgcn_mfma_i32_32x32x32_i8(
                                        bC[s * 2 + j], aF[i][s], acc[i][j], 0, 0, 0);
        } else {
            #pragma unroll
            for (int i = 0; i < 2; ++i)
                #pragma unroll
                for (int j = 0; j < 2; ++j)
                    #pragma unroll
                    for (int s = 0; s < 2; ++s)
                        acc[i][j] = __builtin_amdgcn_mfma_i32_32x32x32_i8(
                                        bN[s * 2 + j], aF[i][s], acc[i][j], 0, 0, 0);
        }
        // epilogue at end of each n-pass; C/D (swapped): m = lane&31 (+i*32),
        // n = (reg&3) + 8*(reg>>2) + 4*(lane>>5) (+j*32).
        if (ks == 15) {
            #pragma unroll
            for (int j = 0; j < 2; ++j)
                #pragma unroll
                for (int q = 0; q < 4; ++q) {
                    const int nb = np * 512 + wv * 64 + j * 32 + q * 8 +
                                   ((ln >> 5) << 2);
                    v4f sc4 = *(const v4f*)&wscale[nb];
                    const v4f bv4 = *(const v4f*)&bias[nb];
                    sc4 *= is;
                    #pragma unroll
                    for (int i = 0; i < 2; ++i) {
                        const int m = mrow0 + i * 32 + lm;
                        v4f o;
                        #pragma unroll
                        for (int r = 0; r < 4; ++r)
                            o[r] = (float)acc[i][j][q * 4 + r] * sc4[r] + bv4[r];
                        *(v4f*)&out[(size_t)m * N_DIM + nb] = o;
                    }
                }
            #pragma unroll
            for (int i = 0; i < 2; ++i)
                #pragma unroll
                for (int j = 0; j < 2; ++j)
                    acc[i][j] = (v16i)(0);
        }
    }
    #undef FBASE
}

extern "C" void kernel_launch(void* const* d_in, const int* in_sizes, int n_in,
                              void* d_out, int out_size, void* d_ws, size_t ws_size,
                              hipStream_t stream)
{
    const float* x       = (const float*)d_in[0];
    const int*   w32     = (const int*)d_in[1];   // int8 weight stored as int32 [N][K]
    const float* wscale  = (const float*)d_in[2];
    const float* iscale  = (const float*)d_in[3];
    const float* bias    = (const float*)d_in[4];
    float* out           = (float*)d_out;

    signed char* wf = (signed char*)d_ws;         // 1 MiB fragment-linear W

    repack_w_kernel<<<(N_DIM * K_DIM / 4) / 256, 256, 0, stream>>>(w32, (int*)wf);

    fused_kernel<<<M_DIM / BM, 512, 0, stream>>>(x, wf, wscale, iscale, bias, out);
}

// Round 14
// 77.935 us; speedup vs baseline: 1.1838x; 1.1838x over previous
//
#include <hip/hip_runtime.h>
#include <stdint.h>
#include <stddef.h>

typedef int   v4i __attribute__((ext_vector_type(4)));
typedef float v4f __attribute__((ext_vector_type(4)));

#define M_DIM 32768
#define N_DIM 1024
#define K_DIM 1024
#define BM 64            // rows per block; block owns [64][1024] of out
#define KSTEPS 16        // K=1024 / 64

// ---------------- pass 0: repack W int32 [N][K] -> fragment-linear int8 -----
// Frag id f = ((np*8 + wv)*16 + ks)*4 + j ; np=n-pass(512 cols), wv=wave,
// j = 16-col subfrag. Lane ln dword dw holds
// W[n = np*512 + wv*64 + j*16 + (ln&15)][k = ks*64 + (ln>>4)*16 + dw*4 ..+4].
__global__ __launch_bounds__(256)
void repack_w_kernel(const int* __restrict__ w32, int* __restrict__ wf)
{
    const int i  = blockIdx.x * 256 + threadIdx.x;   // dword index, < 262144
    const int f  = i >> 8;            // fragment id 0..1023
    const int r  = i & 255;
    const int ln = r >> 2;            // lane 0..63
    const int dw = r & 3;             // dword within 16B
    const int j  = f & 3;
    const int ks = (f >> 2) & 15;
    const int wv = (f >> 6) & 7;
    const int np = f >> 9;
    const int n  = np * 512 + wv * 64 + j * 16 + (ln & 15);
    const int k  = ks * 64 + (ln >> 4) * 16 + dw * 4;
    const v4i v  = *(const v4i*)&w32[(size_t)n * K_DIM + k];
    wf[i] = (v[0] & 255) | ((v[1] & 255) << 8) |
            ((v[2] & 255) << 16) | ((v[3] & 255) << 24);
}

// ---------------- fused: quantize x -> LDS, then int8 GEMM + dequant --------
// 512 threads = 8 waves. Each wave owns [64 rows][64 cols] per n-pass:
// 4x4 of 16x16x64 i8 MFMA (acc 64 AGPR), 2 passes cover N=1024.
// This is the measured-best configuration (R8, 69.6us). Register budget is
// EXACTLY at the 128/wave cap of (512,4): acc 64 + operands/addr 64. Do not
// add cross-kstep prefetch state (R10: spills; R13: 32x32 store inflation).
__global__ __launch_bounds__(512, 4)
void fused_kernel(const float* __restrict__ x,
                  const signed char* __restrict__ Wf,
                  const float* __restrict__ wscale,
                  const float* __restrict__ iscale_p,
                  const float* __restrict__ bias,
                  float* __restrict__ out)
{
    __shared__ signed char lA[BM * K_DIM];   // 64 KiB, swizzled col^((row&7)<<4)

    const int mrow0 = blockIdx.x * BM;
    const int t  = threadIdx.x;
    const int wv = t >> 6;
    const int ln = t & 63;

    // ---- phase 1: load fp32 slab, quantize, swizzled LDS write ----
    {
        const float inv = 1.0f / *iscale_p;
        const int colf = (t & 255) * 4;          // int8/float column
        const int rsub = t >> 8;                 // 0..1
        for (int j = 0; j < 32; ++j) {
            const int row = j * 2 + rsub;
            const v4f v = *(const v4f*)&x[(size_t)(mrow0 + row) * K_DIM + colf];
            int r = 0;
            #pragma unroll
            for (int e = 0; e < 4; ++e) {
                float q = rintf(v[e] * inv);     // round-half-even like jnp
                q = fminf(127.f, fmaxf(-128.f, q));
                r |= ((int)q & 255) << (8 * e);
            }
            *(int*)&lA[row * K_DIM + (colf ^ ((row & 7) << 4))] = r;
        }
    }
    __syncthreads();   // the only barrier: LDS A-tile complete

    const int lr = ln & 15;
    const int kh = (ln >> 4) * 16;
    const float is = *iscale_p;

    for (int np = 0; np < 2; ++np) {
        v4i acc[4][4] = {};
        #pragma unroll 4
        for (int ks = 0; ks < KSTEPS; ++ks) {
            v4i aF[4], bF[4];
            #pragma unroll
            for (int i = 0; i < 4; ++i) {
                const int row = i * 16 + lr;
                aF[i] = *(const v4i*)&lA[row * K_DIM +
                                         ((ks * 64 + kh) ^ ((row & 7) << 4))];
            }
            const size_t fbase = ((size_t)(np * 8 + wv) * 16 + ks) * 4;
            #pragma unroll
            for (int j = 0; j < 4; ++j)
                bF[j] = *(const v4i*)&Wf[(fbase + j) * 1024 + ln * 16];
            #pragma unroll
            for (int i = 0; i < 4; ++i)
                #pragma unroll
                for (int j = 0; j < 4; ++j)
                    acc[i][j] = __builtin_amdgcn_mfma_i32_16x16x64_i8(
                                    aF[i], bF[j], acc[i][j], 0, 0, 0);
        }
        // epilogue for this n-pass: C/D col = ln&15, row = (ln>>4)*4 + r.
        // Nontemporal: out is write-once, never re-read -> skip write-allocate.
        const int c00 = np * 512 + wv * 64;
        #pragma unroll
        for (int j = 0; j < 4; ++j) {
            const int col = c00 + j * 16 + lr;
            const float sc = wscale[col] * is;
            const float bv = bias[col];
            #pragma unroll
            for (int i = 0; i < 4; ++i) {
                const int rowb = mrow0 + i * 16 + ((ln >> 4) << 2);
                #pragma unroll
                for (int r = 0; r < 4; ++r)
                    __builtin_nontemporal_store(
                        (float)acc[i][j][r] * sc + bv,
                        &out[(size_t)(rowb + r) * N_DIM + col]);
            }
        }
    }
}

extern "C" void kernel_launch(void* const* d_in, const int* in_sizes, int n_in,
                              void* d_out, int out_size, void* d_ws, size_t ws_size,
                              hipStream_t stream)
{
    const float* x       = (const float*)d_in[0];
    const int*   w32     = (const int*)d_in[1];   // int8 weight stored as int32 [N][K]
    const float* wscale  = (const float*)d_in[2];
    const float* iscale  = (const float*)d_in[3];
    const float* bias    = (const float*)d_in[4];
    float* out           = (float*)d_out;

    signed char* wf = (signed char*)d_ws;         // 1 MiB fragment-linear W

    repack_w_kernel<<<(N_DIM * K_DIM / 4) / 256, 256, 0, stream>>>(w32, (int*)wf);

    fused_kernel<<<M_DIM / BM, 512, 0, stream>>>(x, wf, wscale, iscale, bias, out);
}

// Round 15
// 69.184 us; speedup vs baseline: 1.3335x; 1.1265x over previous
//
#include <hip/hip_runtime.h>
#include <stdint.h>
#include <stddef.h>

typedef int   v4i __attribute__((ext_vector_type(4)));
typedef float v4f __attribute__((ext_vector_type(4)));

#define M_DIM 32768
#define N_DIM 1024
#define K_DIM 1024
#define BM 64            // rows per block; block owns [64][1024] of out
#define KSTEPS 16        // K=1024 / 64

// ---------------- pass 0: repack W int32 [N][K] -> fragment-linear int8 -----
// Frag id f = ((np*8 + wv)*16 + ks)*4 + j ; np=n-pass(512 cols), wv=wave,
// j = 16-col subfrag. Lane ln dword dw holds
// W[n = np*512 + wv*64 + j*16 + (ln&15)][k = ks*64 + (ln>>4)*16 + dw*4 ..+4].
__global__ __launch_bounds__(256)
void repack_w_kernel(const int* __restrict__ w32, int* __restrict__ wf)
{
    const int i  = blockIdx.x * 256 + threadIdx.x;   // dword index, < 262144
    const int f  = i >> 8;            // fragment id 0..1023
    const int r  = i & 255;
    const int ln = r >> 2;            // lane 0..63
    const int dw = r & 3;             // dword within 16B
    const int j  = f & 3;
    const int ks = (f >> 2) & 15;
    const int wv = (f >> 6) & 7;
    const int np = f >> 9;
    const int n  = np * 512 + wv * 64 + j * 16 + (ln & 15);
    const int k  = ks * 64 + (ln >> 4) * 16 + dw * 4;
    const v4i v  = *(const v4i*)&w32[(size_t)n * K_DIM + k];
    wf[i] = (v[0] & 255) | ((v[1] & 255) << 8) |
            ((v[2] & 255) << 16) | ((v[3] & 255) << 24);
}

// ---------------- fused: quantize x -> LDS, then int8 GEMM + dequant --------
// 512 threads = 8 waves. Each wave owns [64 rows][64 cols] per n-pass:
// 4x4 of 16x16x64 i8 MFMA (acc 64 AGPR), 2 passes cover N=1024.
// Measured-best configuration (R8: 69.6 us). The register budget sits EXACTLY
// at the 128/wave cap of (512,4): acc 64 + operands/addressing ~64. Verified
// dead ends: cross-kstep B prefetch (R10 spill, 4x), 32x32 MFMA (R13 store
// inflation), nt-stores (R14 -12%), store-swap/quant-batch/K-slice (neutral).
__global__ __launch_bounds__(512, 4)
void fused_kernel(const float* __restrict__ x,
                  const signed char* __restrict__ Wf,
                  const float* __restrict__ wscale,
                  const float* __restrict__ iscale_p,
                  const float* __restrict__ bias,
                  float* __restrict__ out)
{
    __shared__ signed char lA[BM * K_DIM];   // 64 KiB, swizzled col^((row&7)<<4)

    const int mrow0 = blockIdx.x * BM;
    const int t  = threadIdx.x;
    const int wv = t >> 6;
    const int ln = t & 63;

    // ---- phase 1: load fp32 slab, quantize, swizzled LDS write ----
    {
        const float inv = 1.0f / *iscale_p;
        const int colf = (t & 255) * 4;          // int8/float column
        const int rsub = t >> 8;                 // 0..1
        for (int j = 0; j < 32; ++j) {
            const int row = j * 2 + rsub;
            const v4f v = *(const v4f*)&x[(size_t)(mrow0 + row) * K_DIM + colf];
            int r = 0;
            #pragma unroll
            for (int e = 0; e < 4; ++e) {
                float q = rintf(v[e] * inv);     // round-half-even like jnp
                q = fminf(127.f, fmaxf(-128.f, q));
                r |= ((int)q & 255) << (8 * e);
            }
            *(int*)&lA[row * K_DIM + (colf ^ ((row & 7) << 4))] = r;
        }
    }
    __syncthreads();   // the only barrier: LDS A-tile complete

    const int lr = ln & 15;
    const int kh = (ln >> 4) * 16;
    const float is = *iscale_p;

    for (int np = 0; np < 2; ++np) {
        v4i acc[4][4] = {};
        #pragma unroll 4
        for (int ks = 0; ks < KSTEPS; ++ks) {
            v4i aF[4], bF[4];
            #pragma unroll
            for (int i = 0; i < 4; ++i) {
                const int row = i * 16 + lr;
                aF[i] = *(const v4i*)&lA[row * K_DIM +
                                         ((ks * 64 + kh) ^ ((row & 7) << 4))];
            }
            const size_t fbase = ((size_t)(np * 8 + wv) * 16 + ks) * 4;
            #pragma unroll
            for (int j = 0; j < 4; ++j)
                bF[j] = *(const v4i*)&Wf[(fbase + j) * 1024 + ln * 16];
            #pragma unroll
            for (int i = 0; i < 4; ++i)
                #pragma unroll
                for (int j = 0; j < 4; ++j)
                    acc[i][j] = __builtin_amdgcn_mfma_i32_16x16x64_i8(
                                    aF[i], bF[j], acc[i][j], 0, 0, 0);
        }
        // epilogue for this n-pass: C/D col = ln&15, row = (ln>>4)*4 + r
        const int c00 = np * 512 + wv * 64;
        #pragma unroll
        for (int j = 0; j < 4; ++j) {
            const int col = c00 + j * 16 + lr;
            const float sc = wscale[col] * is;
            const float bv = bias[col];
            #pragma unroll
            for (int i = 0; i < 4; ++i) {
                const int rowb = mrow0 + i * 16 + ((ln >> 4) << 2);
                #pragma unroll
                for (int r = 0; r < 4; ++r)
                    out[(size_t)(rowb + r) * N_DIM + col] =
                        (float)acc[i][j][r] * sc + bv;
            }
        }
    }
}

extern "C" void kernel_launch(void* const* d_in, const int* in_sizes, int n_in,
                              void* d_out, int out_size, void* d_ws, size_t ws_size,
                              hipStream_t stream)
{
    const float* x       = (const float*)d_in[0];
    const int*   w32     = (const int*)d_in[1];   // int8 weight stored as int32 [N][K]
    const float* wscale  = (const float*)d_in[2];
    const float* iscale  = (const float*)d_in[3];
    const float* bias    = (const float*)d_in[4];
    float* out           = (float*)d_out;

    signed char* wf = (signed char*)d_ws;         // 1 MiB fragment-linear W

    repack_w_kernel<<<(N_DIM * K_DIM / 4) / 256, 256, 0, stream>>>(w32, (int*)wf);

    fused_kernel<<<M_DIM / BM, 512, 0, stream>>>(x, wf, wscale, iscale, bias, out);
}